// Round 3
// baseline (214.318 us; speedup 1.0000x reference)
//
#include <hip/hip_runtime.h>

#define NN 8
#define CC 8
#define TT 600
#define FF 257
#define NF 2056  /* NN * FF */
#define LOADING 7.0710678118654746e-04f /* 0.001/sqrt(2) */

// ---------------------------------------------------------------------------
// Kernel 1: partial noise covariance, 4-wave blocks with LDS tree reduction.
// Block = 256 thr = 4 waves; lane (0..63) -> j = blockIdx.x*64+lane,
// wave (0..3) -> quarter of this block's t-chunk. LDS layout transposed
// red[k][col]: lane stride 4 B -> conflict-free. Noise has zero reuse ->
// non-temporal loads keep L2 for the partial round-trip.
// ---------------------------------------------------------------------------
__global__ __launch_bounds__(256) void cov3_kernel(const float* __restrict__ noise,
                                                   float* __restrict__ partial,
                                                   int tc) {
    __shared__ float red[64][128];  // 32 KB -> 5 blocks/CU
    int lane = threadIdx.x & 63;
    int wave = threadIdx.x >> 6;
    int j = blockIdx.x * 64 + lane;
    int jc = j < NF ? j : NF - 1;  // clamp: dup lanes compute garbage, never store
    int n = jc / FF;
    int f = jc - n * FF;

    int cend = min((int)(blockIdx.y + 1) * tc, TT);
    int tsub = (tc + 3) >> 2;
    int t0 = blockIdx.y * tc + wave * tsub;
    int t1 = min(t0 + tsub, cend);

    const float* base = noise + (size_t)n * (2 * CC * TT * FF) + f;

    float acc[64];
#pragma unroll
    for (int k = 0; k < 64; ++k) acc[k] = 0.f;

#pragma unroll 2
    for (int t = t0; t < t1; ++t) {
        float vr[CC], vi[CC];
#pragma unroll
        for (int c = 0; c < CC; ++c) {
            vr[c] = __builtin_nontemporal_load(&base[(c * TT + t) * FF]);
            vi[c] = __builtin_nontemporal_load(&base[((CC + c) * TT + t) * FF]);
        }
        int p = 0;
#pragma unroll
        for (int c = 0; c < CC; ++c) {
            acc[c] += vr[c] * vr[c] + vi[c] * vi[c];
#pragma unroll
            for (int d2 = c + 1; d2 < CC; ++d2) {
                acc[8 + p] += vr[c] * vr[d2] + vi[c] * vi[d2];   // Re phi[c][d]
                acc[36 + p] += vi[c] * vr[d2] - vr[c] * vi[d2];  // Im phi[c][d]
                ++p;
            }
        }
    }

    // stage 1: waves 2,3 -> LDS; waves 0,1 add
    if (wave >= 2) {
        int col = threadIdx.x - 128;
#pragma unroll
        for (int k = 0; k < 64; ++k) red[k][col] = acc[k];
    }
    __syncthreads();
    if (wave < 2) {
#pragma unroll
        for (int k = 0; k < 64; ++k) acc[k] += red[k][threadIdx.x];
    }
    __syncthreads();
    // stage 2: wave 1 -> LDS; wave 0 adds and stores
    if (wave == 1) {
#pragma unroll
        for (int k = 0; k < 64; ++k) red[k][lane] = acc[k];
    }
    __syncthreads();
    if (wave == 0 && j < NF) {
#pragma unroll
        for (int k = 0; k < 64; ++k) acc[k] += red[k][lane];
        float4* o = (float4*)(partial + ((size_t)blockIdx.y * NF + j) * 64);
#pragma unroll
        for (int k = 0; k < 16; ++k)
            o[k] = make_float4(acc[4 * k], acc[4 * k + 1], acc[4 * k + 2], acc[4 * k + 3]);
    }
}

// ---------------------------------------------------------------------------
// Kernel 2: merged reduce + solve. Block 256 = 4 systems; 64 threads per
// system do a coalesced reduction of the partials, then lane 0 of each wave
// runs the 8x8 complex Gaussian elimination (diagonally dominant ->
// unpivoted safe). Stores conj(w) interleaved [re,im]*8 per (n,f).
// ---------------------------------------------------------------------------
__global__ __launch_bounds__(256) void solve2_kernel(const float* __restrict__ partial,
                                                     const float* __restrict__ steer,
                                                     float* __restrict__ wc,
                                                     int ntc) {
    __shared__ float sphi[4][64];
    int k = threadIdx.x & 63;
    int jj = threadIdx.x >> 6;
    int j = blockIdx.x * 4 + jj;  // grid = 514 -> j < 2056 always

    float s = 0.f;
    for (int c = 0; c < ntc; ++c) s += partial[((size_t)c * NF + j) * 64 + k];
    sphi[jj][k] = s;
    __syncthreads();

    if (k != 0) return;
    int n = j / FF;
    int f = j - n * FF;

    const float invT = 1.0f / (float)TT;
    float Ar[CC][CC], Ai[CC][CC];
    {
        int p = 0;
#pragma unroll
        for (int c = 0; c < CC; ++c) {
            Ar[c][c] = sphi[jj][c] * invT + LOADING;
            Ai[c][c] = LOADING;  // complex diagonal loading
#pragma unroll
            for (int d2 = c + 1; d2 < CC; ++d2) {
                float re = sphi[jj][8 + p] * invT, im = sphi[jj][36 + p] * invT;
                Ar[c][d2] = re;  Ai[c][d2] = im;
                Ar[d2][c] = re;  Ai[d2][c] = -im;
                ++p;
            }
        }
    }

    float dr[CC], di[CC], br[CC], bi[CC];
#pragma unroll
    for (int c = 0; c < CC; ++c) {
        dr[c] = steer[((n * 2 + 0) * FF + f) * CC + c];
        di[c] = steer[((n * 2 + 1) * FF + f) * CC + c];
        br[c] = dr[c];
        bi[c] = di[c];
    }

#pragma unroll
    for (int kk = 0; kk < CC; ++kk) {
        float ar = Ar[kk][kk], ai = Ai[kk][kk];
        float sc = 1.0f / (ar * ar + ai * ai);
        float rr = ar * sc, ri = -ai * sc;
#pragma unroll
        for (int c = kk + 1; c < CC; ++c) {
            float xr0 = Ar[kk][c], xi0 = Ai[kk][c];
            Ar[kk][c] = xr0 * rr - xi0 * ri;
            Ai[kk][c] = xr0 * ri + xi0 * rr;
        }
        {
            float xr0 = br[kk], xi0 = bi[kk];
            br[kk] = xr0 * rr - xi0 * ri;
            bi[kk] = xr0 * ri + xi0 * rr;
        }
#pragma unroll
        for (int i = kk + 1; i < CC; ++i) {
            float mr = Ar[i][kk], mi = Ai[i][kk];
#pragma unroll
            for (int c = kk + 1; c < CC; ++c) {
                float kr = Ar[kk][c], ki = Ai[kk][c];
                Ar[i][c] -= mr * kr - mi * ki;
                Ai[i][c] -= mr * ki + mi * kr;
            }
            float bkr = br[kk], bki = bi[kk];
            br[i] -= mr * bkr - mi * bki;
            bi[i] -= mr * bki + mi * bkr;
        }
    }

    float xr[CC], xi[CC];
#pragma unroll
    for (int kk = CC - 1; kk >= 0; --kk) {
        float sr = br[kk], si = bi[kk];
#pragma unroll
        for (int c = kk + 1; c < CC; ++c) {
            sr -= Ar[kk][c] * xr[c] - Ai[kk][c] * xi[c];
            si -= Ar[kk][c] * xi[c] + Ai[kk][c] * xr[c];
        }
        xr[kk] = sr;
        xi[kk] = si;
    }

    // deno = d^H x: re = dr*xr + di*xi ; im = dr*xi - di*xr
    float der = 0.f, dei = 0.f;
#pragma unroll
    for (int c = 0; c < CC; ++c) {
        der += dr[c] * xr[c] + di[c] * xi[c];
        dei += dr[c] * xi[c] - di[c] * xr[c];
    }
    float sc2 = 1.0f / (der * der + dei * dei);
    float* o = wc + (size_t)j * 16;
#pragma unroll
    for (int c = 0; c < CC; ++c) {
        float qr = (xr[c] * der + xi[c] * dei) * sc2;   // Re(w)
        float qi = (xi[c] * der - xr[c] * dei) * sc2;   // Im(w)
        o[2 * c] = qr;
        o[2 * c + 1] = -qi;  // store conj(w)
    }
}

// ---------------------------------------------------------------------------
// Kernel 3: beamform X[n,t,f] = sum_c wc[n,f,c] * y[n,c,t,f].
// One thread per (n, t-pair, f): w fetched once per 2 outputs (halves the
// L1/L2-side w traffic, which equals the y HBM bytes), 32 y loads in flight.
// y / out are non-temporal (zero reuse).
// ---------------------------------------------------------------------------
__global__ __launch_bounds__(256) void bf2_kernel(const float* __restrict__ mix,
                                                  const float* __restrict__ wc,
                                                  float* __restrict__ out) {
    const int T2 = TT / 2;              // 300
    const int perN = T2 * FF;           // 77100
    int idx = blockIdx.x * 256 + threadIdx.x;
    if (idx >= NN * perN) return;
    int n = idx / perN;
    int rem = idx - n * perN;
    int t2 = rem / FF;
    int f = rem - t2 * FF;
    int t = 2 * t2;

    const float4* w4 = (const float4*)(wc + ((size_t)(n * FF + f)) * 16);
    float4 w0 = w4[0], w1 = w4[1], w2 = w4[2], w3 = w4[3];
    float wr[CC] = {w0.x, w0.z, w1.x, w1.z, w2.x, w2.z, w3.x, w3.z};
    float wi[CC] = {w0.y, w0.w, w1.y, w1.w, w2.y, w2.w, w3.y, w3.w};

    const float* base = mix + (size_t)n * (2 * CC * TT * FF) + t * FF + f;
    float Xr0 = 0.f, Xi0 = 0.f, Xr1 = 0.f, Xi1 = 0.f;
#pragma unroll
    for (int c = 0; c < CC; ++c) {
        const float* br = base + (size_t)c * TT * FF;
        const float* bi = base + (size_t)(CC + c) * TT * FF;
        float yr0 = __builtin_nontemporal_load(br);
        float yi0 = __builtin_nontemporal_load(bi);
        float yr1 = __builtin_nontemporal_load(br + FF);
        float yi1 = __builtin_nontemporal_load(bi + FF);
        Xr0 += wr[c] * yr0 - wi[c] * yi0;
        Xi0 += wr[c] * yi0 + wi[c] * yr0;
        Xr1 += wr[c] * yr1 - wi[c] * yi1;
        Xi1 += wr[c] * yi1 + wi[c] * yr1;
    }
    float* oR = out + ((size_t)(n * 2 + 0) * TT + t) * FF + f;
    float* oI = out + ((size_t)(n * 2 + 1) * TT + t) * FF + f;
    __builtin_nontemporal_store(Xr0, oR);
    __builtin_nontemporal_store(Xr1, oR + FF);
    __builtin_nontemporal_store(Xi0, oI);
    __builtin_nontemporal_store(Xi1, oI + FF);
}

extern "C" void kernel_launch(void* const* d_in, const int* in_sizes, int n_in,
                              void* d_out, int out_size, void* d_ws, size_t ws_size,
                              hipStream_t stream) {
    const float* mixture = (const float*)d_in[0];
    const float* noise = (const float*)d_in[1];
    const float* steer = (const float*)d_in[2];
    float* out = (float*)d_out;

    float* partial = (float*)d_ws;
    size_t per_chunk = (size_t)NF * 64 * sizeof(float);
    size_t wc_bytes = (size_t)NF * 16 * sizeof(float);
    int ntc = 25;
    while (ntc > 1 && per_chunk * (size_t)ntc + wc_bytes > ws_size) --ntc;
    int tc = (TT + ntc - 1) / ntc;
    float* wcp = partial + (size_t)ntc * NF * 64;

    dim3 gcov((NF + 63) / 64, ntc);  // 33 x 25 = 825 blocks of 4 waves
    cov3_kernel<<<gcov, 256, 0, stream>>>(noise, partial, tc);
    solve2_kernel<<<NF / 4, 256, 0, stream>>>(partial, steer, wcp, ntc);
    int total2 = NN * (TT / 2) * FF;
    bf2_kernel<<<(total2 + 255) / 256, 256, 0, stream>>>(mixture, wcp, out);
}

// Round 4
// 200.319 us; speedup vs baseline: 1.0699x; 1.0699x over previous
//
#include <hip/hip_runtime.h>

#define NN 8
#define CC 8
#define TT 600
#define FF 257
#define NF 2056  /* NN * FF */
#define LOADING 7.0710678118654746e-04f /* 0.001/sqrt(2) */

// ---------------------------------------------------------------------------
// Kernel 1: partial noise covariance, 4-wave blocks with LDS tree reduction.
// launch_bounds(256,2): VGPR cap ~256 so acc[64]+vr/vi[16] stay in registers
// (at the default cap of 64 VGPRs the accumulators spill to scratch).
// ---------------------------------------------------------------------------
__global__ __launch_bounds__(256, 2) void cov3_kernel(const float* __restrict__ noise,
                                                      float* __restrict__ partial,
                                                      int tc) {
    __shared__ float red[64][128];  // 32 KB
    int lane = threadIdx.x & 63;
    int wave = threadIdx.x >> 6;
    int j = blockIdx.x * 64 + lane;
    int jc = j < NF ? j : NF - 1;  // clamp: dup lanes compute garbage, never store
    int n = jc / FF;
    int f = jc - n * FF;

    int cend = min((int)(blockIdx.y + 1) * tc, TT);
    int tsub = (tc + 3) >> 2;
    int t0 = blockIdx.y * tc + wave * tsub;
    int t1 = min(t0 + tsub, cend);

    const float* base = noise + (size_t)n * (2 * CC * TT * FF) + f;

    float acc[64];
#pragma unroll
    for (int k = 0; k < 64; ++k) acc[k] = 0.f;

#pragma unroll 2
    for (int t = t0; t < t1; ++t) {
        float vr[CC], vi[CC];
#pragma unroll
        for (int c = 0; c < CC; ++c) {
            vr[c] = __builtin_nontemporal_load(&base[(c * TT + t) * FF]);
            vi[c] = __builtin_nontemporal_load(&base[((CC + c) * TT + t) * FF]);
        }
        int p = 0;
#pragma unroll
        for (int c = 0; c < CC; ++c) {
            acc[c] += vr[c] * vr[c] + vi[c] * vi[c];
#pragma unroll
            for (int d2 = c + 1; d2 < CC; ++d2) {
                acc[8 + p] += vr[c] * vr[d2] + vi[c] * vi[d2];   // Re phi[c][d]
                acc[36 + p] += vi[c] * vr[d2] - vr[c] * vi[d2];  // Im phi[c][d]
                ++p;
            }
        }
    }

    if (wave >= 2) {
        int col = threadIdx.x - 128;
#pragma unroll
        for (int k = 0; k < 64; ++k) red[k][col] = acc[k];
    }
    __syncthreads();
    if (wave < 2) {
#pragma unroll
        for (int k = 0; k < 64; ++k) acc[k] += red[k][threadIdx.x];
    }
    __syncthreads();
    if (wave == 1) {
#pragma unroll
        for (int k = 0; k < 64; ++k) red[k][lane] = acc[k];
    }
    __syncthreads();
    if (wave == 0 && j < NF) {
#pragma unroll
        for (int k = 0; k < 64; ++k) acc[k] += red[k][lane];
        float4* o = (float4*)(partial + ((size_t)blockIdx.y * NF + j) * 64);
#pragma unroll
        for (int k = 0; k < 16; ++k)
            o[k] = make_float4(acc[4 * k], acc[4 * k + 1], acc[4 * k + 2], acc[4 * k + 3]);
    }
}

// ---------------------------------------------------------------------------
// Kernel 2: merged reduce + solve, ROW-PER-LANE parallel GE (no spills).
// Block 256 = 4 systems. Phase 1: 64 thr/system coalesced partial reduction
// into LDS. Phase 2: lanes 0..31 of wave 0; 8 lanes per system, lane = row.
// Each lane holds one row of A (16 floats) + its b/d element -> ~32 VGPRs.
// Pivot row broadcast via __shfl; column-oriented back-substitution;
// group-of-8 shfl_xor reduction for deno = d^H x.
// Stores conj(w) interleaved [re,im]*8 per (n,f).
// ---------------------------------------------------------------------------
__global__ __launch_bounds__(256) void solve3_kernel(const float* __restrict__ partial,
                                                     const float* __restrict__ steer,
                                                     float* __restrict__ wc,
                                                     int ntc) {
    __shared__ float sphi[4][64];
    {
        int k = threadIdx.x & 63;
        int jj = threadIdx.x >> 6;
        int jsys = blockIdx.x * 4 + jj;  // grid = 514 -> < 2056 always
        float s = 0.f;
        for (int c = 0; c < ntc; ++c) s += partial[((size_t)c * NF + jsys) * 64 + k];
        sphi[jj][k] = s;
    }
    __syncthreads();
    if (threadIdx.x >= 32) return;

    int lane = threadIdx.x;
    int sys = lane >> 3;   // 0..3
    int i = lane & 7;      // my row
    int base = sys << 3;   // first lane of my 8-lane group
    int j = blockIdx.x * 4 + sys;
    int n = j / FF;
    int f = j - n * FF;

    const float invT = 1.0f / (float)TT;
    // Build my row from the packed Hermitian (8 diag + 28 re + 28 im).
    float Ar[CC], Ai[CC];
#pragma unroll
    for (int c = 0; c < CC; ++c) {
        if (c == i) {
            Ar[c] = sphi[sys][c] * invT + LOADING;
            Ai[c] = LOADING;  // complex diagonal loading
        } else {
            int lo = i < c ? i : c;
            int hi = i < c ? c : i;
            int p = lo * (15 - lo) / 2 + hi - lo - 1;
            float re = sphi[sys][8 + p] * invT;
            float im = sphi[sys][36 + p] * invT;
            Ar[c] = re;
            Ai[c] = (i > c) ? -im : im;
        }
    }
    float dr = steer[((n * 2 + 0) * FF + f) * CC + i];
    float di = steer[((n * 2 + 1) * FF + f) * CC + i];
    float br = dr, bi = di;

    // Forward elimination (unpivoted; phi is diagonally dominant).
#pragma unroll
    for (int kk = 0; kk < CC; ++kk) {
        float prr = __shfl(Ar[kk], base + kk);
        float pii = __shfl(Ai[kk], base + kk);
        float sc = 1.0f / (prr * prr + pii * pii);
        float rr = prr * sc, ri = -pii * sc;       // 1/pivot
        float mr = Ar[kk], mi = Ai[kk];            // my col-kk element
        bool piv = (i == kk), below = (i > kk);
#pragma unroll
        for (int c = kk + 1; c < CC; ++c) {
            float qr = __shfl(Ar[c], base + kk);   // pivot row element
            float qi = __shfl(Ai[c], base + kk);
            float sr = qr * rr - qi * ri;          // scaled pivot element
            float si = qr * ri + qi * rr;
            if (piv) { Ar[c] = sr; Ai[c] = si; }
            else if (below) {
                Ar[c] -= mr * sr - mi * si;
                Ai[c] -= mr * si + mi * sr;
            }
        }
        float qbr = __shfl(br, base + kk);
        float qbi = __shfl(bi, base + kk);
        float sbr = qbr * rr - qbi * ri;
        float sbi = qbr * ri + qbi * rr;
        if (piv) { br = sbr; bi = sbi; }
        else if (below) {
            br -= mr * sbr - mi * sbi;
            bi -= mr * sbi + mi * sbr;
        }
    }

    // Column-oriented back-substitution: when loop hits kk, (br,bi) on lane
    // kk is x_kk; broadcast and eliminate from rows above.
#pragma unroll
    for (int kk = CC - 1; kk >= 0; --kk) {
        float xkr = __shfl(br, base + kk);
        float xki = __shfl(bi, base + kk);
        if (i < kk) {
            br -= Ar[kk] * xkr - Ai[kk] * xki;
            bi -= Ar[kk] * xki + Ai[kk] * xkr;
        }
    }
    // lane i now holds x_i in (br,bi)

    // deno = d^H x = sum_i conj(d_i) x_i
    float tr = dr * br + di * bi;
    float ti = dr * bi - di * br;
#pragma unroll
    for (int m = 1; m < 8; m <<= 1) {
        tr += __shfl_xor(tr, m);
        ti += __shfl_xor(ti, m);
    }
    float sc2 = 1.0f / (tr * tr + ti * ti);
    float qr = (br * tr + bi * ti) * sc2;   // Re(w_i)
    float qi = (bi * tr - br * ti) * sc2;   // Im(w_i)
    float* o = wc + (size_t)j * 16 + 2 * i;
    o[0] = qr;
    o[1] = -qi;  // store conj(w)
}

// ---------------------------------------------------------------------------
// Kernel 3: beamform X[n,t,f] = sum_c wc[n,f,c] * y[n,c,t,f].
// One thread per (n, t-pair, f); w fetched once per 2 outputs; y/out
// non-temporal (zero reuse).
// ---------------------------------------------------------------------------
__global__ __launch_bounds__(256) void bf2_kernel(const float* __restrict__ mix,
                                                  const float* __restrict__ wc,
                                                  float* __restrict__ out) {
    const int T2 = TT / 2;              // 300
    const int perN = T2 * FF;           // 77100
    int idx = blockIdx.x * 256 + threadIdx.x;
    if (idx >= NN * perN) return;
    int n = idx / perN;
    int rem = idx - n * perN;
    int t2 = rem / FF;
    int f = rem - t2 * FF;
    int t = 2 * t2;

    const float4* w4 = (const float4*)(wc + ((size_t)(n * FF + f)) * 16);
    float4 w0 = w4[0], w1 = w4[1], w2 = w4[2], w3 = w4[3];
    float wr[CC] = {w0.x, w0.z, w1.x, w1.z, w2.x, w2.z, w3.x, w3.z};
    float wi[CC] = {w0.y, w0.w, w1.y, w1.w, w2.y, w2.w, w3.y, w3.w};

    const float* base = mix + (size_t)n * (2 * CC * TT * FF) + t * FF + f;
    float Xr0 = 0.f, Xi0 = 0.f, Xr1 = 0.f, Xi1 = 0.f;
#pragma unroll
    for (int c = 0; c < CC; ++c) {
        const float* br = base + (size_t)c * TT * FF;
        const float* bi = base + (size_t)(CC + c) * TT * FF;
        float yr0 = __builtin_nontemporal_load(br);
        float yi0 = __builtin_nontemporal_load(bi);
        float yr1 = __builtin_nontemporal_load(br + FF);
        float yi1 = __builtin_nontemporal_load(bi + FF);
        Xr0 += wr[c] * yr0 - wi[c] * yi0;
        Xi0 += wr[c] * yi0 + wi[c] * yr0;
        Xr1 += wr[c] * yr1 - wi[c] * yi1;
        Xi1 += wr[c] * yi1 + wi[c] * yr1;
    }
    float* oR = out + ((size_t)(n * 2 + 0) * TT + t) * FF + f;
    float* oI = out + ((size_t)(n * 2 + 1) * TT + t) * FF + f;
    __builtin_nontemporal_store(Xr0, oR);
    __builtin_nontemporal_store(Xr1, oR + FF);
    __builtin_nontemporal_store(Xi0, oI);
    __builtin_nontemporal_store(Xi1, oI + FF);
}

extern "C" void kernel_launch(void* const* d_in, const int* in_sizes, int n_in,
                              void* d_out, int out_size, void* d_ws, size_t ws_size,
                              hipStream_t stream) {
    const float* mixture = (const float*)d_in[0];
    const float* noise = (const float*)d_in[1];
    const float* steer = (const float*)d_in[2];
    float* out = (float*)d_out;

    float* partial = (float*)d_ws;
    size_t per_chunk = (size_t)NF * 64 * sizeof(float);
    size_t wc_bytes = (size_t)NF * 16 * sizeof(float);
    int ntc = 25;
    while (ntc > 1 && per_chunk * (size_t)ntc + wc_bytes > ws_size) --ntc;
    int tc = (TT + ntc - 1) / ntc;
    float* wcp = partial + (size_t)ntc * NF * 64;

    dim3 gcov((NF + 63) / 64, ntc);  // 33 x 25 = 825 blocks of 4 waves
    cov3_kernel<<<gcov, 256, 0, stream>>>(noise, partial, tc);
    solve3_kernel<<<NF / 4, 256, 0, stream>>>(partial, steer, wcp, ntc);
    int total2 = NN * (TT / 2) * FF;
    bf2_kernel<<<(total2 + 255) / 256, 256, 0, stream>>>(mixture, wcp, out);
}